// Round 13
// baseline (538.302 us; speedup 1.0000x reference)
//
#include <hip/hip_runtime.h>
#include <math.h>
#include <stdint.h>

#define NTOK  16384
#define NW6   (NTOK * 6)
#define D4    512              // float4 per full 2048-dim row
#define TPB   64               // tokens per block
#define NBLK  (NTOK / TPB)     // 256 blocks
#define WSEG  2304             // staged W segment: 18 rows x 128 f4 (36,864 B)
#define SCSTR 19               // score LDS stride (18 + 1 pad, bank-clean)

#define DOT4(a, b) ((a).x*(b).x + (a).y*(b).y + (a).z*(b).z + (a).w*(b).w)

// Async global->LDS DMA -- used ONLY for the small W stages now. Rounds
// 5/9/12 showed x-streaming through this path is capped at ~700 GB/s
// device-wide regardless of address pattern; x now goes direct to VGPRs.
#define ASYNC_CP16(gsrc, ldst)                                              \
    __builtin_amdgcn_global_load_lds(                                       \
        (const __attribute__((address_space(1))) void*)(gsrc),              \
        (__attribute__((address_space(3))) void*)(ldst), 16, 0, 0)

// DPP row_shl sum-tree: lane i adds lane i+N (out-of-range -> 0). After 4
// steps lane 0 of each 16-lane row holds the full row sum. (Verified.)
template <int CTRL>
__device__ __forceinline__ float dpp_add(float v) {
    int moved = __builtin_amdgcn_update_dpp(0, __float_as_int(v),
                                            CTRL, 0xF, 0xF, true);
    return v + __int_as_float(moved);
}
__device__ __forceinline__ float row_reduce16(float v) {
    v = dpp_add<0x108>(v);   // row_shl:8
    v = dpp_add<0x104>(v);   // row_shl:4
    v = dpp_add<0x102>(v);   // row_shl:2
    v = dpp_add<0x101>(v);   // row_shl:1
    return v;
}

// Routing math for one token given its 18 full scores (math identical to
// reference `_router`; harness-verified rounds 1, 5-9, 12).
__device__ __forceinline__ void route_one(const float* __restrict__ s,
                                          int tok,
                                          float* __restrict__ out,
                                          unsigned int* __restrict__ lcnt)
{
    const float g0 = 1.f / (1.f + expf(-s[16]));
    const float g1 = 1.f / (1.f + expf(-s[17]));

    // --- Group A: experts 0..7, top-1 of softmax ---
    int aidx = 0; float amax = s[0];
#pragma unroll
    for (int i = 1; i < 8; ++i)
        if (s[i] > amax) { amax = s[i]; aidx = i; }
    float asum = 0.f;
#pragma unroll
    for (int i = 0; i < 8; ++i) asum += expf(s[i] - amax);
    const float a_best = 1.f / asum;

    // --- Group B: experts 8..11, top-1, gated by g0 ---
    int bidx = 0; float bmax = s[8];
#pragma unroll
    for (int i = 1; i < 4; ++i)
        if (s[8 + i] > bmax) { bmax = s[8 + i]; bidx = i; }
    float bsum = 0.f;
#pragma unroll
    for (int i = 0; i < 4; ++i) bsum += expf(s[8 + i] - bmax);
    const float b_w = (g0 > 0.15f) ? ((1.f / bsum) * g0) : 0.f;

    // --- Group C: experts 12..15, top-2 of softmax, gated by g1 ---
    int c1 = 0; float cmax = s[12];
#pragma unroll
    for (int i = 1; i < 4; ++i)
        if (s[12 + i] > cmax) { cmax = s[12 + i]; c1 = i; }
    float csum = 0.f;
#pragma unroll
    for (int i = 0; i < 4; ++i) csum += expf(s[12 + i] - cmax);
    int c2 = -1; float c2v = -1e30f;
#pragma unroll
    for (int i = 0; i < 4; ++i)
        if (i != c1 && s[12 + i] > c2v) { c2v = s[12 + i]; c2 = i; }
    const float cg   = (g1 > 0.15f) ? g1 : 0.f;
    const float c_w1 = (1.f / csum) * cg;
    const float c_w2 = (expf(c2v - cmax) / csum) * cg;

    // --- normalize and write ---
    const float inv = 1.f / (a_best + b_w + c_w1 + c_w2 + 1e-8f);
    float2* ow = reinterpret_cast<float2*>(out + (size_t)tok * 6);
    ow[0] = make_float2(a_best * inv, b_w * inv);
    ow[1] = make_float2(c_w1 * inv, c_w2 * inv);
    ow[2] = make_float2(0.f, 0.f);
    float2* oi = reinterpret_cast<float2*>(out + NW6 + (size_t)tok * 6);
    oi[0] = make_float2((float)aidx, (float)(8 + bidx));
    oi[1] = make_float2((float)(12 + c1), (float)(12 + c2));
    oi[2] = make_float2(0.f, 0.f);

    atomicAdd(&lcnt[aidx], 1u);
    atomicAdd(&lcnt[8 + bidx], 1u);
    atomicAdd(&lcnt[12 + c1], 1u);
    atomicAdd(&lcnt[12 + c2], 1u);
}

// ---------------- Fused: scores over full D + routing + aux ----------------
// 256 blocks x 512 threads x 64 tokens. x streams DIRECT to VGPRs
// (global_load_dwordx4, 2-deep register double-buffer) -- the probe for the
// global_load_lds path cap. W staged in LDS per 512-dim segment (36 KB, 4
// restages with barrier pairs). Expert split: wave w handles experts
// [(w&1)*9, +9) for token set (w>>1)*16 -- halves the W ds_read rate and
// keeps acc at 36 VGPRs (no spill under the 128-VGPR default cap; rounds
// 6-8 lesson). The two halves merge per-token scores through a small LDS
// buffer before the verified routing epilogue.
__global__ __launch_bounds__(512, 1) void fused_router_kernel(
    const float* __restrict__ x,
    const float* __restrict__ We,
    const float* __restrict__ Wg,
    float* __restrict__ out,
    unsigned int* __restrict__ gcounts)
{
    __shared__ float4 smemW[WSEG];          // 36,864 B
    __shared__ float scbuf[TPB * SCSTR];    //  4,864 B
    __shared__ unsigned int lcnt[16];

    const int tid  = threadIdx.x;
    const int wave = tid >> 6;              // 0..7
    const int lane = tid & 63;
    const int l16  = lane & 15;             // 16 dim-slots (4 dims each)
    const int gl   = lane >> 4;             // 4 token-slots per wave-set
    const int h    = wave & 1;              // expert half: 0 -> e0..8, 1 -> e9..17
    const int set  = wave >> 1;             // token set 0..3 (16 tokens each)
    const int tokbase = blockIdx.x * TPB;

    const float4* __restrict__ x4  = reinterpret_cast<const float4*>(x);
    const float4* __restrict__ We4 = reinterpret_cast<const float4*>(We);
    const float4* __restrict__ Wg4 = reinterpret_cast<const float4*>(Wg);

    // Row pointers for this lane's 4 tokens (l16 dim-slot folded in).
    // Per load instruction: 16 lanes read 256 B contiguous from each of the
    // 4 group-rows -> coalesced 4 x 256 B.
    const int row0 = tokbase + set * 16 + gl * 4;
    const float4* rp0 = x4 + (size_t)(row0 + 0) * D4 + l16;
    const float4* rp1 = x4 + (size_t)(row0 + 1) * D4 + l16;
    const float4* rp2 = x4 + (size_t)(row0 + 2) * D4 + l16;
    const float4* rp3 = x4 + (size_t)(row0 + 3) * D4 + l16;

    // Stage W segment seg (18 experts x 512 dims = 36 KB): 8 waves x 64 f4
    // per step, 4.5 steps (step 4 covered by waves 0-3, wave-uniform guard).
    auto stage_W = [&](int seg) {
#pragma unroll
        for (int k = 0; k < 5; ++k) {
            const int base = k * 512 + wave * 64;
            if (base < WSEG) {
                const int idx = base + lane;
                const int e = idx >> 7;                    // 0..17
                const int d = idx & 127;
                const float4* gsrc = ((e < 16) ? (We4 + (size_t)e * D4)
                                               : (Wg4 + (size_t)(e - 16) * D4))
                                     + seg * 128 + d;
                ASYNC_CP16(gsrc, smemW + base);
            }
        }
    };

    float a0[9], a1[9], a2[9], a3[9];
#pragma unroll
    for (int e = 0; e < 9; ++e) { a0[e]=0.f; a1[e]=0.f; a2[e]=0.f; a3[e]=0.f; }

    float4 xA0, xA1, xA2, xA3, xB0, xB1, xB2, xB3;

#define LOADA(K) do { xA0 = rp0[(K)*16]; xA1 = rp1[(K)*16];                 \
                      xA2 = rp2[(K)*16]; xA3 = rp3[(K)*16]; } while (0)
#define LOADB(K) do { xB0 = rp0[(K)*16]; xB1 = rp1[(K)*16];                 \
                      xB2 = rp2[(K)*16]; xB3 = rp3[(K)*16]; } while (0)
// One 64-dim chunk (ch = compile-time 0..7 within segment) for 4 tokens x
// 9 experts: 9 broadcast W reads (2-way bank alias = free) + 144 FMA.
#define COMP(X0, X1, X2, X3, CH) do {                                       \
    _Pragma("unroll")                                                       \
    for (int e = 0; e < 9; ++e) {                                           \
        const float4 w = smemW[(h * 9 + e) * 128 + (CH) * 16 + l16];        \
        a0[e] += DOT4(w, X0); a1[e] += DOT4(w, X1);                         \
        a2[e] += DOT4(w, X2); a3[e] += DOT4(w, X3);                         \
    } } while (0)

    // ---- prologue ----
    stage_W(0);
    LOADA(0); LOADB(1);
    if (tid < 16) lcnt[tid] = 0u;
    __syncthreads();                    // W0 resident (x loads auto-waited)

    for (int seg = 0; seg < 4; ++seg) {
        if (seg) {
            __syncthreads();            // all waves done reading old W
            stage_W(seg);
            __syncthreads();            // vmcnt(0): new W resident
        }
        const int kb = seg * 8;
#pragma unroll
        for (int p = 0; p < 4; ++p) {
            COMP(xA0, xA1, xA2, xA3, 2 * p);
            if (kb + 2 * p + 2 < 32) LOADA(kb + 2 * p + 2);
            COMP(xB0, xB1, xB2, xB3, 2 * p + 1);
            if (kb + 2 * p + 3 < 32) LOADB(kb + 2 * p + 3);
        }
    }

    // ---- reduce 36 sums across each 16-lane group (pure VALU) ----
#pragma unroll
    for (int e = 0; e < 9; ++e) {
        a0[e] = row_reduce16(a0[e]);
        a1[e] = row_reduce16(a1[e]);
        a2[e] = row_reduce16(a2[e]);
        a3[e] = row_reduce16(a3[e]);
    }

    // ---- merge expert halves through LDS ----
    if (l16 == 0) {
        const int tb = set * 16 + gl * 4;
#pragma unroll
        for (int e = 0; e < 9; ++e) {
            scbuf[(tb + 0) * SCSTR + h * 9 + e] = a0[e];
            scbuf[(tb + 1) * SCSTR + h * 9 + e] = a1[e];
            scbuf[(tb + 2) * SCSTR + h * 9 + e] = a2[e];
            scbuf[(tb + 3) * SCSTR + h * 9 + e] = a3[e];
        }
    }
    __syncthreads();

    // ---- routing: one thread per token (wave 0) ----
    if (tid < TPB) {
        float s[18];
#pragma unroll
        for (int e = 0; e < 18; ++e) s[e] = scbuf[tid * SCSTR + e];
        route_one(s, tokbase + tid, out, lcnt);
    }

    __syncthreads();
    if (tid < 16) {
        const unsigned int c = lcnt[tid];
        if (c) atomicAdd(&gcounts[tid], c);
    }
    __syncthreads();

    // Last-block ticket: aux loss. Reference bincount counts the 2 zero-pad
    // indices per token -> expert 0 gets +2*NTOK; total = 6*NTOK.
    if (tid == 0) {
        __threadfence();
        const unsigned int t = atomicAdd(&gcounts[16], 1u);
        if (t == gridDim.x - 1) {
            const float total = 6.0f * (float)NTOK;
            const float uni = 1.0f / 16.0f;
            float aux = 0.f;
            for (int e = 0; e < 16; ++e) {
                float c = (float)atomicAdd(&gcounts[e], 0u)
                          + (e == 0 ? 2.0f * (float)NTOK : 0.0f);
                aux += uni * (logf(uni) - logf(c / total));
            }
            out[2 * NW6] = aux * 0.01f;
        }
    }
#undef LOADA
#undef LOADB
#undef COMP
}

extern "C" void kernel_launch(void* const* d_in, const int* in_sizes, int n_in,
                              void* d_out, int out_size, void* d_ws, size_t ws_size,
                              hipStream_t stream)
{
    const float* x  = (const float*)d_in[0];   // (4,4096,2048)
    const float* We = (const float*)d_in[1];   // (16,2048)
    const float* Wg = (const float*)d_in[2];   // (2,2048)
    float* out = (float*)d_out;

    unsigned int* counts = (unsigned int*)d_ws;

    hipMemsetAsync(counts, 0, 17 * sizeof(unsigned int), stream);

    // Single fused kernel: 256 strips of 64 tokens, 8 waves each.
    fused_router_kernel<<<dim3(NBLK), 512, 0, stream>>>(x, We, Wg, out, counts);
}